// Round 9
// baseline (1065.873 us; speedup 1.0000x reference)
//
#include <hip/hip_runtime.h>

#define E_  768
#define N_  3072
#define L_  4
#define H_  12
#define FF_ 3072
#define LDQKV 2304
#define SCL_ 0.052058744f   // log2(e)/sqrt(768)

typedef short bf16x8 __attribute__((ext_vector_type(8)));
typedef short s16x4  __attribute__((ext_vector_type(4)));
typedef float f32x4  __attribute__((ext_vector_type(4)));
typedef __fp16 h16x2 __attribute__((ext_vector_type(2)));
typedef _Float16 f16x4 __attribute__((ext_vector_type(4)));

__device__ __forceinline__ short f2bf(float f) {
  union { float f; unsigned u; } v; v.f = f;
  unsigned r = v.u + 0x7fffu + ((v.u >> 16) & 1u);   // RNE to bf16
  return (short)(r >> 16);
}
__device__ __forceinline__ float bf2f(short s) {
  union { unsigned u; float f; } v; v.u = ((unsigned)(unsigned short)s) << 16;
  return v.f;
}

__device__ __forceinline__ void gld_lds16(const void* g, void* l) {
  __builtin_amdgcn_global_load_lds(
      (const __attribute__((address_space(1))) unsigned int*)g,
      (__attribute__((address_space(3))) unsigned int*)l, 16, 0, 0);
}

// ---------------- bf16 GEMM: C = A[.,lda] * B[.,ldb]^T, split-K, fused Vt ------
__global__ __launch_bounds__(256) void gemm_bt_kernel(
    const short* __restrict__ A, const short* __restrict__ B,
    const float* __restrict__ bias, float* __restrict__ Cf,
    short* __restrict__ Cb, _Float16* __restrict__ Vt,
    int Nd, int lda, int ldb, int kcnt, size_t czstride, int relu)
{
  alignas(16) __shared__ short As[128 * 32];
  alignas(16) __shared__ short Bs[128 * 32];
  const int tid = threadIdx.x;
  const int w = tid >> 6, lane = tid & 63;
  const int quad = lane >> 4, cl = lane & 15;
  const int wr = w >> 1, wc = w & 1;
  const int row0 = blockIdx.y * 128, col0 = blockIdx.x * 128;
  const int koff = blockIdx.z * kcnt;
  A += koff; B += koff;
  if (Cf) Cf += (size_t)blockIdx.z * czstride;
  const int srow = lane >> 2;
  const int scol = (((lane & 3) ^ ((lane >> 3) & 3)) * 8);
  const int rsw = (quad ^ ((cl >> 1) & 3)) * 8;
  const f32x4 fz = {0.f, 0.f, 0.f, 0.f};
  f32x4 acc[4][4];
#pragma unroll
  for (int i = 0; i < 4; i++)
#pragma unroll
    for (int j = 0; j < 4; j++) acc[i][j] = fz;

  const int nk = kcnt >> 5;
  for (int kt = 0; kt < nk; kt++) {
    const int k0 = kt << 5;
#pragma unroll
    for (int i = 0; i < 2; i++) {
      const int chunk = w * 2 + i;
      gld_lds16(A + (size_t)(row0 + chunk * 16 + srow) * lda + k0 + scol, As + chunk * 512);
      gld_lds16(B + (size_t)(col0 + chunk * 16 + srow) * ldb + k0 + scol, Bs + chunk * 512);
    }
    __syncthreads();
    bf16x8 af[4], bfr[4];
#pragma unroll
    for (int mt = 0; mt < 4; mt++)
      af[mt] = *(const bf16x8*)(As + (wr * 64 + mt * 16 + cl) * 32 + rsw);
#pragma unroll
    for (int nt = 0; nt < 4; nt++)
      bfr[nt] = *(const bf16x8*)(Bs + (wc * 64 + nt * 16 + cl) * 32 + rsw);
#pragma unroll
    for (int mt = 0; mt < 4; mt++)
#pragma unroll
      for (int nt = 0; nt < 4; nt++)
        acc[mt][nt] = __builtin_amdgcn_mfma_f32_16x16x32_bf16(af[mt], bfr[nt], acc[mt][nt], 0, 0, 0);
    __syncthreads();
  }
#pragma unroll
  for (int mt = 0; mt < 4; mt++)
#pragma unroll
    for (int nt = 0; nt < 4; nt++) {
      const int col = col0 + wc * 64 + nt * 16 + cl;
      const float bv = bias ? bias[col] : 0.f;
#pragma unroll
      for (int r = 0; r < 4; r++) {
        const int row = row0 + wr * 64 + mt * 16 + quad * 4 + r;
        float v2 = acc[mt][nt][r] + bv;
        if (relu) v2 = fmaxf(v2, 0.f);
        if (Cf) Cf[(size_t)row * Nd + col] = v2;
        if (Cb) Cb[(size_t)row * Nd + col] = f2bf(v2);
      }
      if (Vt && col >= 1536) {   // fused V transpose: Vt[d][n], 4 consecutive n
        const int d = col - 1536;
        const int rowb = row0 + wr * 64 + mt * 16 + quad * 4;
        f16x4 vo;
#pragma unroll
        for (int r = 0; r < 4; r++) vo[r] = (_Float16)acc[mt][nt][r];
        *(f16x4*)(Vt + (size_t)d * N_ + rowb) = vo;
      }
    }
}

// ---------------- flash attention: barrier-free wave-private split-K -----------
// Each wave owns k-range [s*1536 + w*384, +384), covers all 64 q rows.
// 24 iters of 16 k; wave-private LDS staging; explicit vmcnt ordering, no
// barriers in the loop (compiler does NOT order plain LDS reads vs the DMA).
__global__ __launch_bounds__(256) void flash_kernel(
    const short* __restrict__ QKV, const _Float16* __restrict__ Vt,
    float* __restrict__ Op, float* __restrict__ Ml)
{
  alignas(16) __shared__ short KV[16640];   // 4 waves x (K 2x1KH + V 2x1KH) + l-area
  const int tid = threadIdx.x;
  const int w = tid >> 6, lane = tid & 63;
  const int quad = lane >> 4, cl = lane & 15;
  const int q0 = blockIdx.x * 64, h = blockIdx.y, s = blockIdx.z;
  const int hoff = h * 64;
  const f32x4 fz = {0.f, 0.f, 0.f, 0.f};

  // Q fragments: all 64 q rows (B-operand of 16x16x32 bf16)
  bf16x8 bq[4][2];
#pragma unroll
  for (int qt = 0; qt < 4; qt++)
#pragma unroll
    for (int c = 0; c < 2; c++)
      bq[qt][c] = *(const bf16x8*)(QKV + (size_t)(q0 + qt * 16 + cl) * LDQKV + hoff + c * 32 + quad * 8);

  // staging source pointers (wave-private k-range)
  const int kr0 = s * 1536 + w * 384;
  const short* kp0 = QKV + (size_t)(kr0 + (lane >> 3)) * LDQKV + 768 + hoff + ((lane & 7) ^ (lane >> 3)) * 8;
  const short* kp1 = kp0 + 8 * LDQKV;
  const _Float16* vp0 = Vt + (size_t)(hoff + (lane >> 1)) * N_ + kr0 + (lane & 1) * 8;
  const _Float16* vp1 = vp0 + 32 * N_;
  short* kb0 = KV + w * 4096;
  short* kb1 = KV + w * 4096 + 1024;
  short* vb0 = KV + w * 4096 + 2048;
  short* vb1 = KV + w * 4096 + 3072;

  f32x4 Oa[16];
#pragma unroll
  for (int t = 0; t < 16; t++) Oa[t] = fz;
  float l4[4] = {0.f, 0.f, 0.f, 0.f};

  // prologue: stage iter 0 into buf 0
  gld_lds16(kp0, kb0); gld_lds16(kp1, kb0 + 512);
  gld_lds16(vp0, vb0); gld_lds16(vp1, vb0 + 512);
  kp0 += 16 * LDQKV; kp1 += 16 * LDQKV; vp0 += 16; vp1 += 16;

  for (int it = 0; it < 24; it++) {
    const int cur = it & 1;
    // unconditional prefetch (it==23 prefetches dead-but-allocated memory) so
    // outstanding-DMA count at the wait below is always: 4 (cur, oldest) + 4 (next)
    {
      short* kn = cur ? kb0 : kb1;
      short* vn = cur ? vb0 : vb1;
      gld_lds16(kp0, kn); gld_lds16(kp1, kn + 512);
      gld_lds16(vp0, vn); gld_lds16(vp1, vn + 512);
      kp0 += 16 * LDQKV; kp1 += 16 * LDQKV; vp0 += 16; vp1 += 16;
    }
    // wait for all but the newest 4 vmem ops -> current buffer's DMAs complete
    asm volatile("s_waitcnt vmcnt(4)" ::: "memory");
    const short* kc = (cur ? kb1 : kb0) + cl * 64;
    const _Float16* vc = (const _Float16*)(cur ? vb1 : vb0);
    const bf16x8 ak0 = *(const bf16x8*)(kc + ((quad ^ (cl & 7)) * 8));
    const bf16x8 ak1 = *(const bf16x8*)(kc + (((quad + 4) ^ (cl & 7)) * 8));
    f32x4 S[4];
#pragma unroll
    for (int qt = 0; qt < 4; qt++) {
      f32x4 z = fz;
      z = __builtin_amdgcn_mfma_f32_16x16x32_bf16(ak0, bq[qt][0], z, 0, 0, 0);
      S[qt] = __builtin_amdgcn_mfma_f32_16x16x32_bf16(ak1, bq[qt][1], z, 0, 0, 0);
    }
    f16x4 pf[4];
#pragma unroll
    for (int qt = 0; qt < 4; qt++) {
      const float p0 = __builtin_amdgcn_exp2f(S[qt][0]);
      const float p1 = __builtin_amdgcn_exp2f(S[qt][1]);
      const float p2 = __builtin_amdgcn_exp2f(S[qt][2]);
      const float p3 = __builtin_amdgcn_exp2f(S[qt][3]);
      l4[qt] += (p0 + p1) + (p2 + p3);
      const h16x2 lo = __builtin_amdgcn_cvt_pkrtz(p0, p1);
      const h16x2 hi = __builtin_amdgcn_cvt_pkrtz(p2, p3);
      pf[qt][0] = (_Float16)lo[0]; pf[qt][1] = (_Float16)lo[1];
      pf[qt][2] = (_Float16)hi[0]; pf[qt][3] = (_Float16)hi[1];
    }
#pragma unroll
    for (int dt = 0; dt < 4; dt++) {
      const f16x4 av = *(const f16x4*)(vc + dt * 256 + cl * 16 + quad * 4);
#pragma unroll
      for (int qt = 0; qt < 4; qt++)
        Oa[dt * 4 + qt] = __builtin_amdgcn_mfma_f32_16x16x16f16(av, pf[qt], Oa[dt * 4 + qt], 0, 0, 0);
    }
  }
  // cross-quad (k) reduce of l
#pragma unroll
  for (int qt = 0; qt < 4; qt++) {
    l4[qt] += __shfl_xor(l4[qt], 16);
    l4[qt] += __shfl_xor(l4[qt], 32);
  }

  // drain the (dead) final prefetch before reusing the staging LDS
  asm volatile("s_waitcnt vmcnt(0)" ::: "memory");

  // in-block combine of the 4 wave partials -> 1 partial per block
  float* comb = (float*)KV;
  float* lA = (float*)(KV + 16384);   // 64 floats
  float* lB = lA + 64;
  __syncthreads();   // staging region dead from here
  if (w & 1) {
    float* dst = comb + (w == 1 ? 0 : 4096);
#pragma unroll
    for (int t = 0; t < 16; t++) *(f32x4*)(dst + t * 256 + lane * 4) = Oa[t];
    float* ld = (w == 1) ? lA : lB;
    if (quad == 0)
#pragma unroll
      for (int qt = 0; qt < 4; qt++) ld[qt * 16 + cl] = l4[qt];
  }
  __syncthreads();
  if (w == 0) {
#pragma unroll
    for (int t = 0; t < 16; t++) {
      const f32x4 o = *(const f32x4*)(comb + t * 256 + lane * 4);
#pragma unroll
      for (int r = 0; r < 4; r++) Oa[t][r] += o[r];
    }
#pragma unroll
    for (int qt = 0; qt < 4; qt++) l4[qt] += lA[qt * 16 + cl];
  }
  if (w == 2) {
#pragma unroll
    for (int t = 0; t < 16; t++) {
      const f32x4 o = *(const f32x4*)(comb + 4096 + t * 256 + lane * 4);
#pragma unroll
      for (int r = 0; r < 4; r++) Oa[t][r] += o[r];
    }
#pragma unroll
    for (int qt = 0; qt < 4; qt++) l4[qt] += lB[qt * 16 + cl];
  }
  __syncthreads();
  if (w == 2) {
#pragma unroll
    for (int t = 0; t < 16; t++) *(f32x4*)(comb + t * 256 + lane * 4) = Oa[t];
    if (quad == 0)
#pragma unroll
      for (int qt = 0; qt < 4; qt++) lA[qt * 16 + cl] = l4[qt];
  }
  __syncthreads();
  if (w == 0) {
#pragma unroll
    for (int t = 0; t < 16; t++) {
      const f32x4 o = *(const f32x4*)(comb + t * 256 + lane * 4);
#pragma unroll
      for (int r = 0; r < 4; r++) Oa[t][r] += o[r];
    }
#pragma unroll
    for (int qt = 0; qt < 4; qt++) l4[qt] += lA[qt * 16 + cl];
    // store block partial (split s)
    float* opb = Op + (size_t)s * (N_ * E_);
#pragma unroll
    for (int qt = 0; qt < 4; qt++) {
      float* oprow = opb + (size_t)(q0 + qt * 16 + cl) * E_ + hoff;
#pragma unroll
      for (int dt = 0; dt < 4; dt++)
#pragma unroll
        for (int r = 0; r < 4; r++)
          oprow[dt * 16 + quad * 4 + r] = Oa[dt * 4 + qt][r];
    }
    if (quad == 0)
#pragma unroll
      for (int qt = 0; qt < 4; qt++)
        Ml[((size_t)s * H_ + h) * N_ + q0 + qt * 16 + cl] = l4[qt];
  }
}

// ---------------- merge 2 split partials -> bf16 attention output --------------
__global__ __launch_bounds__(256) void merge_kernel(
    const float* __restrict__ Op, const float* __restrict__ Ml,
    short* __restrict__ atb)
{
  const int idx = blockIdx.x * 256 + threadIdx.x;   // over N_*192
  const int n = idx / 192, c4 = idx % 192;
  const int e0 = c4 * 4, h = e0 >> 6;
  float den = 0.f;
  f32x4 num = {0.f, 0.f, 0.f, 0.f};
#pragma unroll
  for (int s = 0; s < 2; s++) {
    den += Ml[((size_t)s * H_ + h) * N_ + n];
    const f32x4 o = *(const f32x4*)(Op + ((size_t)s * N_ + n) * E_ + e0);
#pragma unroll
    for (int j = 0; j < 4; j++) num[j] += o[j];
  }
  const float inv = 1.f / den;
  s16x4 ob;
#pragma unroll
  for (int j = 0; j < 4; j++) ob[j] = f2bf(num[j] * inv);
  *(s16x4*)(atb + (size_t)n * E_ + e0) = ob;
}

// ---------------- wordenc finalize: trunc(p0+p1+bw) + pos ----------------------
__global__ __launch_bounds__(256) void wordenc_fin_kernel(
    const float* __restrict__ p0, const float* __restrict__ p1,
    const float* __restrict__ bw, const float* __restrict__ pos,
    float* __restrict__ of, short* __restrict__ ob)
{
  const int idx = blockIdx.x * 256 + threadIdx.x;     // over NE/4
  const size_t e4 = (size_t)idx * 4;
  const int cc = (int)(e4 % E_);
  const f32x4 a = *(const f32x4*)(p0 + e4);
  const f32x4 b = *(const f32x4*)(p1 + e4);
  const f32x4 bwv = *(const f32x4*)(bw + cc);
  const f32x4 pv = *(const f32x4*)(pos + e4);
  f32x4 o; s16x4 obv;
#pragma unroll
  for (int j = 0; j < 4; j++) {
    o[j] = truncf(a[j] + b[j] + bwv[j]) + pv[j];
    obv[j] = f2bf(o[j]);
  }
  *(f32x4*)(of + e4) = o;
  *(s16x4*)(ob + e4) = obv;
}

// ---------------- residual + layernorm (4 partials + residual + opt bias) ------
__global__ __launch_bounds__(256) void resid_ln_kernel(
    const float* __restrict__ a0, const float* __restrict__ a1,
    const float* __restrict__ a2, const float* __restrict__ a3,
    const float* __restrict__ b,
    const float* __restrict__ g, const float* __restrict__ bet,
    const float* __restrict__ bias,
    float* __restrict__ of, short* __restrict__ ob)
{
  const int row = blockIdx.x, tid = threadIdx.x;
  const int w = tid >> 6, lane = tid & 63;
  __shared__ float red[8];
  const size_t base = (size_t)row * E_;
  float v[3]; float s = 0.f;
#pragma unroll
  for (int j = 0; j < 3; j++) {
    const int cc = tid + j * 256;
    float t = (a0[base + cc] + a1[base + cc]) + (a2[base + cc] + a3[base + cc]) + b[base + cc];
    if (bias) t += bias[cc];
    v[j] = t;
    s += t;
  }
#pragma unroll
  for (int msk = 1; msk < 64; msk <<= 1) s += __shfl_xor(s, msk);
  if (lane == 0) red[w] = s;
  __syncthreads();
  const float mean = (red[0] + red[1] + red[2] + red[3]) * (1.f / E_);
  float s2 = 0.f;
#pragma unroll
  for (int j = 0; j < 3; j++) { const float d = v[j] - mean; s2 += d * d; }
#pragma unroll
  for (int msk = 1; msk < 64; msk <<= 1) s2 += __shfl_xor(s2, msk);
  if (lane == 0) red[4 + w] = s2;
  __syncthreads();
  const float var = (red[4] + red[5] + red[6] + red[7]) * (1.f / E_);
  const float rstd = rsqrtf(var + 1e-5f);
#pragma unroll
  for (int j = 0; j < 3; j++) {
    const int cc = tid + j * 256;
    const float o = (v[j] - mean) * rstd * g[cc] + bet[cc];
    of[base + cc] = o;
    ob[base + cc] = f2bf(o);
  }
}

// ---------------- one-shot prep: weight converts + hi/lo packs (x2 per thread) --
__global__ __launch_bounds__(256) void prep_kernel(
    const float* __restrict__ Wq, const float* __restrict__ Wk,
    const float* __restrict__ Wv, const float* __restrict__ Wo,
    const float* __restrict__ W1, const float* __restrict__ W2,
    const float* __restrict__ Ww, const float* __restrict__ x,
    short* __restrict__ wqkv, short* __restrict__ wo_b,
    short* __restrict__ w1_b, short* __restrict__ w2_b,
    short* __restrict__ whl, short* __restrict__ xhl)
{
  const int idx = blockIdx.x * 256 + threadIdx.x;
  const int EEg = 589824;           // L*E*E/4
  const int FEg = 2359296;          // L*FF*E/4
#pragma unroll
  for (int u = 0; u < 2; u++) {
    int g = idx * 2 + u;
    if (g < 3 * EEg) {
      const int which = g / EEg;
      const int gi = g - which * EEg;
      const float* src = which == 0 ? Wq : (which == 1 ? Wk : Wv);
      const float scale = which == 0 ? SCL_ : 1.f;
      const size_t e4 = (size_t)gi * 4;
      const int lidx = (int)(e4 / (E_ * E_));
      const size_t rem = e4 % (E_ * E_);
      const f32x4 v = *(const f32x4*)(src + e4);
      s16x4 o;
#pragma unroll
      for (int q = 0; q < 4; q++) o[q] = f2bf(v[q] * scale);
      *(s16x4*)(wqkv + ((size_t)lidx * 3 + which) * E_ * E_ + rem) = o;
      continue;
    }
    g -= 3 * EEg;
    if (g < EEg) {
      const size_t e4 = (size_t)g * 4;
      const f32x4 v = *(const f32x4*)(Wo + e4);
      s16x4 o;
#pragma unroll
      for (int q = 0; q < 4; q++) o[q] = f2bf(v[q]);
      *(s16x4*)(wo_b + e4) = o;
      continue;
    }
    g -= EEg;
    if (g < FEg) {
      const size_t e4 = (size_t)g * 4;
      const f32x4 v = *(const f32x4*)(W1 + e4);
      s16x4 o;
#pragma unroll
      for (int q = 0; q < 4; q++) o[q] = f2bf(v[q]);
      *(s16x4*)(w1_b + e4) = o;
      continue;
    }
    g -= FEg;
    if (g < FEg) {
      const size_t e4 = (size_t)g * 4;
      const f32x4 v = *(const f32x4*)(W2 + e4);
      s16x4 o;
#pragma unroll
      for (int q = 0; q < 4; q++) o[q] = f2bf(v[q]);
      *(s16x4*)(w2_b + e4) = o;
      continue;
    }
    g -= FEg;
    if (g < 147456) {   // Wword pack: whl[c] = [hi | hi | lo]
      const size_t e4 = (size_t)g * 4;
      const int c = (int)(e4 / E_);
      const int k = (int)(e4 % E_);
      const f32x4 v = *(const f32x4*)(Ww + e4);
      s16x4 hi, lo;
#pragma unroll
      for (int q = 0; q < 4; q++) {
        hi[q] = f2bf(v[q]);
        lo[q] = f2bf(v[q] - bf2f(hi[q]));
      }
      short* base = whl + (size_t)c * LDQKV + k;
      *(s16x4*)(base) = hi;
      *(s16x4*)(base + 768) = hi;
      *(s16x4*)(base + 1536) = lo;
      continue;
    }
    g -= 147456;
    {                  // x pack: xhl[n] = [hi | lo | hi]
      const size_t e4 = (size_t)g * 4;
      const int n = (int)(e4 / E_);
      const int k = (int)(e4 % E_);
      const f32x4 v = *(const f32x4*)(x + e4);
      s16x4 hi, lo;
#pragma unroll
      for (int q = 0; q < 4; q++) {
        hi[q] = f2bf(v[q]);
        lo[q] = f2bf(v[q] - bf2f(hi[q]));
      }
      short* base = xhl + (size_t)n * LDQKV + k;
      *(s16x4*)(base) = hi;
      *(s16x4*)(base + 768) = lo;
      *(s16x4*)(base + 1536) = hi;
    }
  }
}

// ---------------- column mean ----------------------------------------------------
__global__ void colmean_kernel(const float* __restrict__ src, float* __restrict__ out)
{
  const int c = blockIdx.x * 256 + threadIdx.x;
  const int r0 = blockIdx.y * 128;
  float s = 0.f;
  for (int r = 0; r < 128; r++) s += src[(size_t)(r0 + r) * E_ + c];
  atomicAdd(&out[c], s * (1.f / N_));
}

extern "C" void kernel_launch(void* const* d_in, const int* in_sizes, int n_in,
                              void* d_out, int out_size, void* d_ws, size_t ws_size,
                              hipStream_t stream)
{
  (void)in_sizes; (void)n_in; (void)out_size; (void)ws_size;
  const float* x     = (const float*)d_in[0];
  const float* Wword = (const float*)d_in[2];
  const float* bword = (const float*)d_in[3];
  const float* pos   = (const float*)d_in[4];
  const float* Wq    = (const float*)d_in[5];
  const float* Wk    = (const float*)d_in[6];
  const float* Wv    = (const float*)d_in[7];
  const float* Wo    = (const float*)d_in[8];
  const float* W1    = (const float*)d_in[9];
  const float* b1    = (const float*)d_in[10];
  const float* W2    = (const float*)d_in[11];
  const float* b2    = (const float*)d_in[12];
  const float* g1    = (const float*)d_in[13];
  const float* be1   = (const float*)d_in[14];
  const float* g2    = (const float*)d_in[15];
  const float* be2   = (const float*)d_in[16];

  char* p = (char*)d_ws;
  auto take = [&](size_t bytes) { char* q = p; p += (bytes + 255) & ~(size_t)255; return q; };
  const size_t EE = (size_t)E_ * E_;
  const size_t NE = (size_t)N_ * E_;
  const size_t FE = (size_t)FF_ * E_;

  short* wqkv_b = (short*)take(L_ * 3 * EE * 2);
  short* wo_b   = (short*)take(L_ * EE * 2);
  short* w1_b   = (short*)take(L_ * FE * 2);
  short* w2_b   = (short*)take(L_ * FE * 2);
  short* whl    = (short*)take((size_t)E_ * LDQKV * 2);
  float* outf   = (float*)take(NE * 4);
  short* outb   = (short*)take(NE * 2);
  float* xmf    = (float*)take(NE * 4);      // doubles as Vt (f16) early in layer
  short* xmb    = (short*)take(NE * 2);
  short* qkvb   = (short*)take((size_t)N_ * LDQKV * 2);   // also xhl at t=0
  float* Op     = (float*)take(4 * NE * 4);  // flash partials | Wo partials | y1b
  float* part4  = (float*)take(4 * NE * 4);  // FF2 partials
  float* Ml     = (float*)take((size_t)2 * H_ * N_ * 4);

  short* xhl  = qkvb;
  short* y1b  = (short*)Op;                  // N*FF bf16 = first half of Op region
  _Float16* vtb = (_Float16*)xmf;
  short* atb  = outb;

  prep_kernel<<<dim3(15264), dim3(256), 0, stream>>>(
      Wq, Wk, Wv, Wo, W1, W2, Wword, x,
      wqkv_b, wo_b, w1_b, w2_b, whl, xhl);

  // word encoding: emulated-fp32 GEMM (split-K 2) + finalize
  gemm_bt_kernel<<<dim3(6, 24, 2), dim3(256), 0, stream>>>(
      xhl, whl, nullptr, Op, nullptr, nullptr, E_, LDQKV, LDQKV, 1152, NE, 0);
  wordenc_fin_kernel<<<dim3(2304), dim3(256), 0, stream>>>(
      Op, Op + NE, bword, pos, outf, outb);

  for (int l = 0; l < L_; l++) {
    gemm_bt_kernel<<<dim3(18, 24, 1), dim3(256), 0, stream>>>(
        outb, wqkv_b + l * 3 * EE, nullptr, nullptr, qkvb, vtb, LDQKV, E_, E_, E_, 0, 0);
    flash_kernel<<<dim3(48, 12, 2), dim3(256), 0, stream>>>(qkvb, vtb, Op, Ml);
    merge_kernel<<<dim3(2304), dim3(256), 0, stream>>>(Op, Ml, atb);
    gemm_bt_kernel<<<dim3(6, 24, 4), dim3(256), 0, stream>>>(
        atb, wo_b + l * EE, nullptr, Op, nullptr, nullptr, E_, E_, E_, 192, NE, 0);
    resid_ln_kernel<<<dim3(N_), dim3(256), 0, stream>>>(
        Op, Op + NE, Op + 2 * NE, Op + 3 * NE, outf,
        g1 + l * E_, be1 + l * E_, nullptr, xmf, xmb);
    gemm_bt_kernel<<<dim3(24, 24, 1), dim3(256), 0, stream>>>(
        xmb, w1_b + l * FE, b1 + l * FF_, nullptr, y1b, nullptr, FF_, E_, E_, E_, 0, 1);
    gemm_bt_kernel<<<dim3(6, 24, 4), dim3(256), 0, stream>>>(
        y1b, w2_b + l * FE, nullptr, part4, nullptr, nullptr, E_, FF_, FF_, 768, NE, 0);
    resid_ln_kernel<<<dim3(N_), dim3(256), 0, stream>>>(
        part4, part4 + NE, part4 + 2 * NE, part4 + 3 * NE, xmf,
        g2 + l * E_, be2 + l * E_, b2 + l * E_, outf, outb);
  }
  hipMemsetAsync(d_out, 0, E_ * sizeof(float), stream);
  colmean_kernel<<<dim3(3, 24), dim3(256), 0, stream>>>(outf, (float*)d_out);
}

// Round 10
// 997.649 us; speedup vs baseline: 1.0684x; 1.0684x over previous
//
#include <hip/hip_runtime.h>

#define E_  768
#define N_  3072
#define L_  4
#define H_  12
#define FF_ 3072
#define LDQKV 2304
#define SCL_ 0.052058744f   // log2(e)/sqrt(768)

typedef short bf16x8 __attribute__((ext_vector_type(8)));
typedef short s16x4  __attribute__((ext_vector_type(4)));
typedef float f32x4  __attribute__((ext_vector_type(4)));
typedef __fp16 h16x2 __attribute__((ext_vector_type(2)));
typedef _Float16 f16x4 __attribute__((ext_vector_type(4)));

__device__ __forceinline__ short f2bf(float f) {
  union { float f; unsigned u; } v; v.f = f;
  unsigned r = v.u + 0x7fffu + ((v.u >> 16) & 1u);   // RNE to bf16
  return (short)(r >> 16);
}
__device__ __forceinline__ float bf2f(short s) {
  union { unsigned u; float f; } v; v.u = ((unsigned)(unsigned short)s) << 16;
  return v.f;
}

__device__ __forceinline__ void gld_lds16(const void* g, void* l) {
  __builtin_amdgcn_global_load_lds(
      (const __attribute__((address_space(1))) unsigned int*)g,
      (__attribute__((address_space(3))) unsigned int*)l, 16, 0, 0);
}

// ---------------- bf16 GEMM 128x128: C = A * B^T, split-K, fp32/bf16 out -------
__global__ __launch_bounds__(256) void gemm_bt_kernel(
    const short* __restrict__ A, const short* __restrict__ B,
    const float* __restrict__ bias, float* __restrict__ Cf,
    short* __restrict__ Cb, _Float16* __restrict__ Vt,
    int Nd, int lda, int ldb, int kcnt, size_t czstride, int relu)
{
  alignas(16) __shared__ short As[128 * 32];
  alignas(16) __shared__ short Bs[128 * 32];
  const int tid = threadIdx.x;
  const int w = tid >> 6, lane = tid & 63;
  const int quad = lane >> 4, cl = lane & 15;
  const int wr = w >> 1, wc = w & 1;
  const int row0 = blockIdx.y * 128, col0 = blockIdx.x * 128;
  const int koff = blockIdx.z * kcnt;
  A += koff; B += koff;
  if (Cf) Cf += (size_t)blockIdx.z * czstride;
  const int srow = lane >> 2;
  const int scol = (((lane & 3) ^ ((lane >> 3) & 3)) * 8);
  const int rsw = (quad ^ ((cl >> 1) & 3)) * 8;
  const f32x4 fz = {0.f, 0.f, 0.f, 0.f};
  f32x4 acc[4][4];
#pragma unroll
  for (int i = 0; i < 4; i++)
#pragma unroll
    for (int j = 0; j < 4; j++) acc[i][j] = fz;

  const int nk = kcnt >> 5;
  for (int kt = 0; kt < nk; kt++) {
    const int k0 = kt << 5;
#pragma unroll
    for (int i = 0; i < 2; i++) {
      const int chunk = w * 2 + i;
      gld_lds16(A + (size_t)(row0 + chunk * 16 + srow) * lda + k0 + scol, As + chunk * 512);
      gld_lds16(B + (size_t)(col0 + chunk * 16 + srow) * ldb + k0 + scol, Bs + chunk * 512);
    }
    __syncthreads();
    bf16x8 af[4], bfr[4];
#pragma unroll
    for (int mt = 0; mt < 4; mt++)
      af[mt] = *(const bf16x8*)(As + (wr * 64 + mt * 16 + cl) * 32 + rsw);
#pragma unroll
    for (int nt = 0; nt < 4; nt++)
      bfr[nt] = *(const bf16x8*)(Bs + (wc * 64 + nt * 16 + cl) * 32 + rsw);
#pragma unroll
    for (int mt = 0; mt < 4; mt++)
#pragma unroll
      for (int nt = 0; nt < 4; nt++)
        acc[mt][nt] = __builtin_amdgcn_mfma_f32_16x16x32_bf16(af[mt], bfr[nt], acc[mt][nt], 0, 0, 0);
    __syncthreads();
  }
#pragma unroll
  for (int mt = 0; mt < 4; mt++)
#pragma unroll
    for (int nt = 0; nt < 4; nt++) {
      const int col = col0 + wc * 64 + nt * 16 + cl;
      const float bv = bias ? bias[col] : 0.f;
#pragma unroll
      for (int r = 0; r < 4; r++) {
        const int row = row0 + wr * 64 + mt * 16 + quad * 4 + r;
        float v2 = acc[mt][nt][r] + bv;
        if (relu) v2 = fmaxf(v2, 0.f);
        if (Cf) Cf[(size_t)row * Nd + col] = v2;
        if (Cb) Cb[(size_t)row * Nd + col] = f2bf(v2);
      }
      if (Vt && col >= 1536) {
        const int d = col - 1536;
        const int rowb = row0 + wr * 64 + mt * 16 + quad * 4;
        f16x4 vo;
#pragma unroll
        for (int r = 0; r < 4; r++) vo[r] = (_Float16)acc[mt][nt][r];
        *(f16x4*)(Vt + (size_t)d * N_ + rowb) = vo;
      }
    }
}

// ---------------- bf16 GEMM 128x64: for grid-starved thin GEMMs (QKV, FF1) -----
// 4 waves stacked in M (32 rows each); acc[2][4] = 32 VGPRs; 12 KB LDS.
__global__ __launch_bounds__(256) void gemm64_kernel(
    const short* __restrict__ A, const short* __restrict__ B,
    const float* __restrict__ bias, short* __restrict__ Cb,
    _Float16* __restrict__ Vt, int Nd, int lda, int ldb, int kcnt, int relu)
{
  alignas(16) __shared__ short As[128 * 32];
  alignas(16) __shared__ short Bs[64 * 32];
  const int tid = threadIdx.x;
  const int w = tid >> 6, lane = tid & 63;
  const int quad = lane >> 4, cl = lane & 15;
  const int row0 = blockIdx.y * 128, col0 = blockIdx.x * 64;
  const int srow = lane >> 2;
  const int scol = (((lane & 3) ^ ((lane >> 3) & 3)) * 8);
  const int rsw = (quad ^ ((cl >> 1) & 3)) * 8;
  const f32x4 fz = {0.f, 0.f, 0.f, 0.f};
  f32x4 acc[2][4];
#pragma unroll
  for (int i = 0; i < 2; i++)
#pragma unroll
    for (int j = 0; j < 4; j++) acc[i][j] = fz;

  const int nk = kcnt >> 5;
  for (int kt = 0; kt < nk; kt++) {
    const int k0 = kt << 5;
#pragma unroll
    for (int i = 0; i < 2; i++) {
      const int chunk = w * 2 + i;
      gld_lds16(A + (size_t)(row0 + chunk * 16 + srow) * lda + k0 + scol, As + chunk * 512);
    }
    gld_lds16(B + (size_t)(col0 + w * 16 + srow) * ldb + k0 + scol, Bs + w * 512);
    __syncthreads();
    bf16x8 af[2], bfr[4];
#pragma unroll
    for (int mt = 0; mt < 2; mt++)
      af[mt] = *(const bf16x8*)(As + (w * 32 + mt * 16 + cl) * 32 + rsw);
#pragma unroll
    for (int nt = 0; nt < 4; nt++)
      bfr[nt] = *(const bf16x8*)(Bs + (nt * 16 + cl) * 32 + rsw);
#pragma unroll
    for (int mt = 0; mt < 2; mt++)
#pragma unroll
      for (int nt = 0; nt < 4; nt++)
        acc[mt][nt] = __builtin_amdgcn_mfma_f32_16x16x32_bf16(af[mt], bfr[nt], acc[mt][nt], 0, 0, 0);
    __syncthreads();
  }
#pragma unroll
  for (int mt = 0; mt < 2; mt++)
#pragma unroll
    for (int nt = 0; nt < 4; nt++) {
      const int col = col0 + nt * 16 + cl;
      const float bv = bias ? bias[col] : 0.f;
#pragma unroll
      for (int r = 0; r < 4; r++) {
        const int row = row0 + w * 32 + mt * 16 + quad * 4 + r;
        float v2 = acc[mt][nt][r] + bv;
        if (relu) v2 = fmaxf(v2, 0.f);
        Cb[(size_t)row * Nd + col] = f2bf(v2);
      }
      if (Vt && col >= 1536) {
        const int d = col - 1536;
        const int rowb = row0 + w * 32 + mt * 16 + quad * 4;
        f16x4 vo;
#pragma unroll
        for (int r = 0; r < 4; r++) vo[r] = (_Float16)acc[mt][nt][r];
        *(f16x4*)(Vt + (size_t)d * N_ + rowb) = vo;
      }
    }
}

// ---------------- flash attention (R7 proven version): block tiles, split-K ----
__global__ __launch_bounds__(256) void flash_kernel(
    const short* __restrict__ QKV, const _Float16* __restrict__ Vt,
    float* __restrict__ Op, float* __restrict__ Ml)
{
  alignas(16) __shared__ short Ks[64 * 64];
  alignas(16) __shared__ _Float16 Vs[64 * 64];
  const int tid = threadIdx.x;
  const int w = tid >> 6, lane = tid & 63;
  const int quad = lane >> 4, cl = lane & 15;
  const int q0 = blockIdx.x * 64, h = blockIdx.y, s = blockIdx.z;
  const int hoff = h * 64;
  const f32x4 fz = {0.f, 0.f, 0.f, 0.f};
  const int qrow = q0 + w * 16 + cl;
  const short* qp = QKV + (size_t)qrow * LDQKV + hoff;
  const bf16x8 bq0 = *(const bf16x8*)(qp + quad * 8);
  const bf16x8 bq1 = *(const bf16x8*)(qp + 32 + quad * 8);

  const int strow = lane >> 3;
  const int stcol = ((lane & 7) ^ strow) * 8;
  const short* kp0 = QKV + (size_t)(s * 768 + w * 16 + strow) * LDQKV + 768 + hoff + stcol;
  const short* kp1 = kp0 + 8 * LDQKV;
  const _Float16* vp0 = Vt + (size_t)(hoff + w * 16 + strow) * N_ + s * 768 + stcol;
  const _Float16* vp1 = vp0 + 8 * N_;
  short* ksd = Ks + w * 1024;
  _Float16* vsd = Vs + w * 1024;

  const int swz = cl & 7;
  const short* kf0 = Ks + cl * 64 + ((quad ^ swz) * 8);
  const short* kf1 = Ks + cl * 64 + (((quad + 4) ^ swz) * 8);
  const _Float16* vf0 = Vs + cl * 64 + (((0 + (quad >> 1)) ^ swz) * 8) + (quad & 1) * 4;
  const _Float16* vf1 = Vs + cl * 64 + (((2 + (quad >> 1)) ^ swz) * 8) + (quad & 1) * 4;
  const _Float16* vf2 = Vs + cl * 64 + (((4 + (quad >> 1)) ^ swz) * 8) + (quad & 1) * 4;
  const _Float16* vf3 = Vs + cl * 64 + (((6 + (quad >> 1)) ^ swz) * 8) + (quad & 1) * 4;

  f32x4 Oa[4];
#pragma unroll
  for (int t = 0; t < 4; t++) Oa[t] = fz;
  float l = 0.f;

  for (int kb = 0; kb < 12; kb++) {
    gld_lds16(kp0, ksd);
    gld_lds16(kp1, ksd + 512);
    gld_lds16(vp0, vsd);
    gld_lds16(vp1, vsd + 512);
    kp0 += 64 * LDQKV; kp1 += 64 * LDQKV; vp0 += 64; vp1 += 64;
    __syncthreads();
    f32x4 S[4];
#pragma unroll
    for (int t = 0; t < 4; t++) {
      const bf16x8 ak0 = *(const bf16x8*)(kf0 + t * 1024);
      const bf16x8 ak1 = *(const bf16x8*)(kf1 + t * 1024);
      f32x4 z = fz;
      z = __builtin_amdgcn_mfma_f32_16x16x32_bf16(ak0, bq0, z, 0, 0, 0);
      S[t] = __builtin_amdgcn_mfma_f32_16x16x32_bf16(ak1, bq1, z, 0, 0, 0);
    }
    f16x4 pf[4];
#pragma unroll
    for (int t = 0; t < 4; t++) {
      const float p0 = __builtin_amdgcn_exp2f(S[t][0]);
      const float p1 = __builtin_amdgcn_exp2f(S[t][1]);
      const float p2 = __builtin_amdgcn_exp2f(S[t][2]);
      const float p3 = __builtin_amdgcn_exp2f(S[t][3]);
      l += (p0 + p1) + (p2 + p3);
      const h16x2 lo = __builtin_amdgcn_cvt_pkrtz(p0, p1);
      const h16x2 hi = __builtin_amdgcn_cvt_pkrtz(p2, p3);
      pf[t][0] = (_Float16)lo[0]; pf[t][1] = (_Float16)lo[1];
      pf[t][2] = (_Float16)hi[0]; pf[t][3] = (_Float16)hi[1];
    }
#pragma unroll
    for (int td = 0; td < 4; td++) {
      Oa[td] = __builtin_amdgcn_mfma_f32_16x16x16f16(*(const f16x4*)(vf0 + td * 1024), pf[0], Oa[td], 0, 0, 0);
      Oa[td] = __builtin_amdgcn_mfma_f32_16x16x16f16(*(const f16x4*)(vf1 + td * 1024), pf[1], Oa[td], 0, 0, 0);
      Oa[td] = __builtin_amdgcn_mfma_f32_16x16x16f16(*(const f16x4*)(vf2 + td * 1024), pf[2], Oa[td], 0, 0, 0);
      Oa[td] = __builtin_amdgcn_mfma_f32_16x16x16f16(*(const f16x4*)(vf3 + td * 1024), pf[3], Oa[td], 0, 0, 0);
    }
    __syncthreads();
  }
  l += __shfl_xor(l, 16);
  l += __shfl_xor(l, 32);
  float* op = Op + ((size_t)s * N_ + qrow) * E_ + hoff;
#pragma unroll
  for (int td = 0; td < 4; td++)
#pragma unroll
    for (int r = 0; r < 4; r++)
      op[td * 16 + quad * 4 + r] = Oa[td][r];
  if (quad == 0)
    Ml[((size_t)s * H_ + h) * N_ + qrow] = l;
}

// ---------------- merge 4 split partials -> bf16 attention output --------------
__global__ __launch_bounds__(256) void merge_kernel(
    const float* __restrict__ Op, const float* __restrict__ Ml,
    short* __restrict__ atb)
{
  const int idx = blockIdx.x * 256 + threadIdx.x;   // over N_*192
  const int n = idx / 192, c4 = idx % 192;
  const int e0 = c4 * 4, h = e0 >> 6;
  float den = 0.f;
  f32x4 num = {0.f, 0.f, 0.f, 0.f};
#pragma unroll
  for (int s = 0; s < 4; s++) {
    den += Ml[((size_t)s * H_ + h) * N_ + n];
    const f32x4 o = *(const f32x4*)(Op + ((size_t)s * N_ + n) * E_ + e0);
#pragma unroll
    for (int j = 0; j < 4; j++) num[j] += o[j];
  }
  const float inv = 1.f / den;
  s16x4 ob;
#pragma unroll
  for (int j = 0; j < 4; j++) ob[j] = f2bf(num[j] * inv);
  *(s16x4*)(atb + (size_t)n * E_ + e0) = ob;
}

// ---------------- wordenc finalize: trunc(p0+p1+bw) + pos ----------------------
__global__ __launch_bounds__(256) void wordenc_fin_kernel(
    const float* __restrict__ p0, const float* __restrict__ p1,
    const float* __restrict__ bw, const float* __restrict__ pos,
    float* __restrict__ of, short* __restrict__ ob)
{
  const int idx = blockIdx.x * 256 + threadIdx.x;     // over NE/4
  const size_t e4 = (size_t)idx * 4;
  const int cc = (int)(e4 % E_);
  const f32x4 a = *(const f32x4*)(p0 + e4);
  const f32x4 b = *(const f32x4*)(p1 + e4);
  const f32x4 bwv = *(const f32x4*)(bw + cc);
  const f32x4 pv = *(const f32x4*)(pos + e4);
  f32x4 o; s16x4 obv;
#pragma unroll
  for (int j = 0; j < 4; j++) {
    o[j] = truncf(a[j] + b[j] + bwv[j]) + pv[j];
    obv[j] = f2bf(o[j]);
  }
  *(f32x4*)(of + e4) = o;
  *(s16x4*)(ob + e4) = obv;
}

// ---------------- residual + layernorm (4 partials + residual + opt bias) ------
__global__ __launch_bounds__(256) void resid_ln_kernel(
    const float* __restrict__ a0, const float* __restrict__ a1,
    const float* __restrict__ a2, const float* __restrict__ a3,
    const float* __restrict__ b,
    const float* __restrict__ g, const float* __restrict__ bet,
    const float* __restrict__ bias,
    float* __restrict__ of, short* __restrict__ ob)
{
  const int row = blockIdx.x, tid = threadIdx.x;
  const int w = tid >> 6, lane = tid & 63;
  __shared__ float red[8];
  const size_t base = (size_t)row * E_;
  float v[3]; float s = 0.f;
#pragma unroll
  for (int j = 0; j < 3; j++) {
    const int cc = tid + j * 256;
    float t = (a0[base + cc] + a1[base + cc]) + (a2[base + cc] + a3[base + cc]) + b[base + cc];
    if (bias) t += bias[cc];
    v[j] = t;
    s += t;
  }
#pragma unroll
  for (int msk = 1; msk < 64; msk <<= 1) s += __shfl_xor(s, msk);
  if (lane == 0) red[w] = s;
  __syncthreads();
  const float mean = (red[0] + red[1] + red[2] + red[3]) * (1.f / E_);
  float s2 = 0.f;
#pragma unroll
  for (int j = 0; j < 3; j++) { const float d = v[j] - mean; s2 += d * d; }
#pragma unroll
  for (int msk = 1; msk < 64; msk <<= 1) s2 += __shfl_xor(s2, msk);
  if (lane == 0) red[4 + w] = s2;
  __syncthreads();
  const float var = (red[4] + red[5] + red[6] + red[7]) * (1.f / E_);
  const float rstd = rsqrtf(var + 1e-5f);
#pragma unroll
  for (int j = 0; j < 3; j++) {
    const int cc = tid + j * 256;
    const float o = (v[j] - mean) * rstd * g[cc] + bet[cc];
    of[base + cc] = o;
    ob[base + cc] = f2bf(o);
  }
}

// ---------------- one-shot prep: weight converts + hi/lo packs (x2 per thread) --
__global__ __launch_bounds__(256) void prep_kernel(
    const float* __restrict__ Wq, const float* __restrict__ Wk,
    const float* __restrict__ Wv, const float* __restrict__ Wo,
    const float* __restrict__ W1, const float* __restrict__ W2,
    const float* __restrict__ Ww, const float* __restrict__ x,
    short* __restrict__ wqkv, short* __restrict__ wo_b,
    short* __restrict__ w1_b, short* __restrict__ w2_b,
    short* __restrict__ whl, short* __restrict__ xhl)
{
  const int idx = blockIdx.x * 256 + threadIdx.x;
  const int EEg = 589824;           // L*E*E/4
  const int FEg = 2359296;          // L*FF*E/4
#pragma unroll
  for (int u = 0; u < 2; u++) {
    int g = idx * 2 + u;
    if (g < 3 * EEg) {
      const int which = g / EEg;
      const int gi = g - which * EEg;
      const float* src = which == 0 ? Wq : (which == 1 ? Wk : Wv);
      const float scale = which == 0 ? SCL_ : 1.f;
      const size_t e4 = (size_t)gi * 4;
      const int lidx = (int)(e4 / (E_ * E_));
      const size_t rem = e4 % (E_ * E_);
      const f32x4 v = *(const f32x4*)(src + e4);
      s16x4 o;
#pragma unroll
      for (int q = 0; q < 4; q++) o[q] = f2bf(v[q] * scale);
      *(s16x4*)(wqkv + ((size_t)lidx * 3 + which) * E_ * E_ + rem) = o;
      continue;
    }
    g -= 3 * EEg;
    if (g < EEg) {
      const size_t e4 = (size_t)g * 4;
      const f32x4 v = *(const f32x4*)(Wo + e4);
      s16x4 o;
#pragma unroll
      for (int q = 0; q < 4; q++) o[q] = f2bf(v[q]);
      *(s16x4*)(wo_b + e4) = o;
      continue;
    }
    g -= EEg;
    if (g < FEg) {
      const size_t e4 = (size_t)g * 4;
      const f32x4 v = *(const f32x4*)(W1 + e4);
      s16x4 o;
#pragma unroll
      for (int q = 0; q < 4; q++) o[q] = f2bf(v[q]);
      *(s16x4*)(w1_b + e4) = o;
      continue;
    }
    g -= FEg;
    if (g < FEg) {
      const size_t e4 = (size_t)g * 4;
      const f32x4 v = *(const f32x4*)(W2 + e4);
      s16x4 o;
#pragma unroll
      for (int q = 0; q < 4; q++) o[q] = f2bf(v[q]);
      *(s16x4*)(w2_b + e4) = o;
      continue;
    }
    g -= FEg;
    if (g < 147456) {   // Wword pack: whl[c] = [hi | hi | lo]
      const size_t e4 = (size_t)g * 4;
      const int c = (int)(e4 / E_);
      const int k = (int)(e4 % E_);
      const f32x4 v = *(const f32x4*)(Ww + e4);
      s16x4 hi, lo;
#pragma unroll
      for (int q = 0; q < 4; q++) {
        hi[q] = f2bf(v[q]);
        lo[q] = f2bf(v[q] - bf2f(hi[q]));
      }
      short* base = whl + (size_t)c * LDQKV + k;
      *(s16x4*)(base) = hi;
      *(s16x4*)(base + 768) = hi;
      *(s16x4*)(base + 1536) = lo;
      continue;
    }
    g -= 147456;
    {                  // x pack: xhl[n] = [hi | lo | hi]
      const size_t e4 = (size_t)g * 4;
      const int n = (int)(e4 / E_);
      const int k = (int)(e4 % E_);
      const f32x4 v = *(const f32x4*)(x + e4);
      s16x4 hi, lo;
#pragma unroll
      for (int q = 0; q < 4; q++) {
        hi[q] = f2bf(v[q]);
        lo[q] = f2bf(v[q] - bf2f(hi[q]));
      }
      short* base = xhl + (size_t)n * LDQKV + k;
      *(s16x4*)(base) = hi;
      *(s16x4*)(base + 768) = lo;
      *(s16x4*)(base + 1536) = hi;
    }
  }
}

// ---------------- column mean ----------------------------------------------------
__global__ void colmean_kernel(const float* __restrict__ src, float* __restrict__ out)
{
  const int c = blockIdx.x * 256 + threadIdx.x;
  const int r0 = blockIdx.y * 128;
  float s = 0.f;
  for (int r = 0; r < 128; r++) s += src[(size_t)(r0 + r) * E_ + c];
  atomicAdd(&out[c], s * (1.f / N_));
}

extern "C" void kernel_launch(void* const* d_in, const int* in_sizes, int n_in,
                              void* d_out, int out_size, void* d_ws, size_t ws_size,
                              hipStream_t stream)
{
  (void)in_sizes; (void)n_in; (void)out_size; (void)ws_size;
  const float* x     = (const float*)d_in[0];
  const float* Wword = (const float*)d_in[2];
  const float* bword = (const float*)d_in[3];
  const float* pos   = (const float*)d_in[4];
  const float* Wq    = (const float*)d_in[5];
  const float* Wk    = (const float*)d_in[6];
  const float* Wv    = (const float*)d_in[7];
  const float* Wo    = (const float*)d_in[8];
  const float* W1    = (const float*)d_in[9];
  const float* b1    = (const float*)d_in[10];
  const float* W2    = (const float*)d_in[11];
  const float* b2    = (const float*)d_in[12];
  const float* g1    = (const float*)d_in[13];
  const float* be1   = (const float*)d_in[14];
  const float* g2    = (const float*)d_in[15];
  const float* be2   = (const float*)d_in[16];

  char* p = (char*)d_ws;
  auto take = [&](size_t bytes) { char* q = p; p += (bytes + 255) & ~(size_t)255; return q; };
  const size_t EE = (size_t)E_ * E_;
  const size_t NE = (size_t)N_ * E_;
  const size_t FE = (size_t)FF_ * E_;

  short* wqkv_b = (short*)take(L_ * 3 * EE * 2);
  short* wo_b   = (short*)take(L_ * EE * 2);
  short* w1_b   = (short*)take(L_ * FE * 2);
  short* w2_b   = (short*)take(L_ * FE * 2);
  short* whl    = (short*)take((size_t)E_ * LDQKV * 2);
  float* outf   = (float*)take(NE * 4);
  short* outb   = (short*)take(NE * 2);
  float* xmf    = (float*)take(NE * 4);      // doubles as Vt (f16) early in layer
  short* xmb    = (short*)take(NE * 2);
  short* qkvb   = (short*)take((size_t)N_ * LDQKV * 2);   // also xhl at t=0
  float* Op     = (float*)take(4 * NE * 4);  // flash partials | Wo partials | y1b
  float* part4  = (float*)take(4 * NE * 4);  // FF2 partials
  float* Ml     = (float*)take((size_t)4 * H_ * N_ * 4);

  short* xhl  = qkvb;
  short* y1b  = (short*)Op;                  // N*FF bf16 = first half of Op region
  _Float16* vtb = (_Float16*)xmf;
  short* atb  = outb;

  prep_kernel<<<dim3(15264), dim3(256), 0, stream>>>(
      Wq, Wk, Wv, Wo, W1, W2, Wword, x,
      wqkv_b, wo_b, w1_b, w2_b, whl, xhl);

  // word encoding: emulated-fp32 GEMM (split-K 2) + finalize
  gemm_bt_kernel<<<dim3(6, 24, 2), dim3(256), 0, stream>>>(
      xhl, whl, nullptr, Op, nullptr, nullptr, E_, LDQKV, LDQKV, 1152, NE, 0);
  wordenc_fin_kernel<<<dim3(2304), dim3(256), 0, stream>>>(
      Op, Op + NE, bword, pos, outf, outb);

  for (int l = 0; l < L_; l++) {
    gemm64_kernel<<<dim3(36, 24), dim3(256), 0, stream>>>(
        outb, wqkv_b + l * 3 * EE, nullptr, qkvb, vtb, LDQKV, E_, E_, E_, 0);
    flash_kernel<<<dim3(48, 12, 4), dim3(256), 0, stream>>>(qkvb, vtb, Op, Ml);
    merge_kernel<<<dim3(2304), dim3(256), 0, stream>>>(Op, Ml, atb);
    gemm_bt_kernel<<<dim3(6, 24, 4), dim3(256), 0, stream>>>(
        atb, wo_b + l * EE, nullptr, Op, nullptr, nullptr, E_, E_, E_, 192, NE, 0);
    resid_ln_kernel<<<dim3(N_), dim3(256), 0, stream>>>(
        Op, Op + NE, Op + 2 * NE, Op + 3 * NE, outf,
        g1 + l * E_, be1 + l * E_, nullptr, xmf, xmb);
    gemm64_kernel<<<dim3(48, 24), dim3(256), 0, stream>>>(
        xmb, w1_b + l * FE, b1 + l * FF_, y1b, nullptr, FF_, E_, E_, E_, 1);
    gemm_bt_kernel<<<dim3(6, 24, 4), dim3(256), 0, stream>>>(
        y1b, w2_b + l * FE, nullptr, part4, nullptr, nullptr, E_, FF_, FF_, 768, NE, 0);
    resid_ln_kernel<<<dim3(N_), dim3(256), 0, stream>>>(
        part4, part4 + NE, part4 + 2 * NE, part4 + 3 * NE, xmf,
        g2 + l * E_, be2 + l * E_, b2 + l * E_, outf, outb);
  }
  hipMemsetAsync(d_out, 0, E_ * sizeof(float), stream);
  colmean_kernel<<<dim3(3, 24), dim3(256), 0, stream>>>(outf, (float*)d_out);
}